// Round 5
// baseline (1157.705 us; speedup 1.0000x reference)
//
#include <hip/hip_runtime.h>

#define B_  512
#define S_  200
#define E_  512
#define A_  256
#define V_  50000
#define K_  51
#define PADIDX 1

typedef short short8_t __attribute__((ext_vector_type(8)));
typedef float float4_t __attribute__((ext_vector_type(4)));
typedef unsigned short u16;
typedef unsigned int   u32;

// ---------- f32 -> bf16 RNE (internal staging only; outputs are f32!) ----------
__device__ __forceinline__ u16 f2b(float f) {
    u32 x = __float_as_uint(f);
    return (u16)((x + 0x7fffu + ((x >> 16) & 1u)) >> 16);
}

// ---------- async global->LDS, 16B per lane (bf16 source only) ----------
__device__ __forceinline__ void glds16(const u16* g, short* l) {
    __builtin_amdgcn_global_load_lds(
        (const __attribute__((address_space(1))) unsigned int*)g,
        (__attribute__((address_space(3))) unsigned int*)l, 16, 0, 0);
}

// ---------- workspace offsets (bytes); NO region aliasing ----------
#define GP2_OFF   0ull
#define GP2_BYTES 67141632ull          // 131136 rows * 256 bf16 (64-row halo slack)
#define AP_OFF    67141632ull          // packed conv weights: 408*8192 bf16
#define RT_OFF    73826304ull          // 1/||T_a||   (256 f32)
#define RX_OFF    73827328ull          // 1/||xx_c||  (102400 f32)
#define M_OFF     74236928ull          // m[b,s]      (102400 f32)
#define T16_OFF   75056128ull          // T in bf16 (512KB) -- exclusive region
#define WS_NEEDED 76628992ull

// ================= T (f32) -> bf16 =================
__global__ __launch_bounds__(256) void k_cvtT(const float* __restrict__ Tf, u16* __restrict__ T16) {
    int o = (blockIdx.x * 256 + threadIdx.x) * 4;
    float4 d = *(const float4*)(Tf + o);
    ushort4 r;
    r.x = f2b(d.x); r.y = f2b(d.y); r.z = f2b(d.z); r.w = f2b(d.w);
    *(ushort4*)(T16 + o) = r;
}

// ================= 1/||T_a|| (f32) =================
__global__ __launch_bounds__(64) void k_tnorm(const float* __restrict__ Tf, float* __restrict__ rt) {
    int a = blockIdx.x, l = threadIdx.x;
    float4 d0 = *(const float4*)(Tf + (size_t)a * E_ + l * 8);
    float4 d1 = *(const float4*)(Tf + (size_t)a * E_ + l * 8 + 4);
    float s = d0.x*d0.x + d0.y*d0.y + d0.z*d0.z + d0.w*d0.w
            + d1.x*d1.x + d1.y*d1.y + d1.z*d1.z + d1.w*d1.w;
#pragma unroll
    for (int off = 32; off >= 1; off >>= 1) s += __shfl_xor(s, off, 64);
    if (l == 0) rt[a] = (s > 0.f) ? 1.0f / sqrtf(s) : 0.0f;
}

// ================= 1/||emb[x_c]|| (f32) =================
__global__ __launch_bounds__(256) void k_xnorm(const int* __restrict__ x, const float* __restrict__ embf,
                                               float* __restrict__ rx) {
    int c = blockIdx.x * 4 + (threadIdx.x >> 6);
    int l = threadIdx.x & 63;
    size_t base = (size_t)x[c] * E_ + l * 8;
    float4 d0 = *(const float4*)(embf + base);
    float4 d1 = *(const float4*)(embf + base + 4);
    float s = d0.x*d0.x + d0.y*d0.y + d0.z*d0.z + d0.w*d0.w
            + d1.x*d1.x + d1.y*d1.y + d1.z*d1.z + d1.w*d1.w;
#pragma unroll
    for (int off = 32; off >= 1; off >>= 1) s += __shfl_xor(s, off, 64);
    if (l == 0) rx[c] = (s > 0.f) ? 1.0f / sqrtf(s) : 0.0f;
}

// ========= pack conv_w[a][i][k] (f32) -> ap[kb][a][j] bf16  (r=k*256+i, kb=r/32, j=r%32)
__global__ __launch_bounds__(256) void k_prepack(const float* __restrict__ cwf, u16* __restrict__ ap) {
    int o  = blockIdx.x * 256 + threadIdx.x;
    int kb = o >> 13, a = (o >> 5) & 255, j = o & 31;
    int i  = ((kb & 7) << 5) + j;
    int k  = kb >> 3;
    ap[o] = f2b(cwf[(size_t)a * (A_ * K_) + (size_t)i * K_ + k]);
}

// ================= g = cosine(T, emb[x])  -> gp2[c2][a] bf16 =================
__global__ __launch_bounds__(256) void k_ggemm(const int* __restrict__ x, const float* __restrict__ embf,
                                               const u16* __restrict__ T16, const float* __restrict__ rt,
                                               const float* __restrict__ rx, u16* __restrict__ gp2) {
    __shared__ __align__(16) short Xs[64 * 32];
    __shared__ __align__(16) short Ts[256 * 32];
    int t = threadIdx.x, l = t & 63, w = t >> 6;
    int c0 = blockIdx.x * 64;
    int crow  = t >> 2;
    int xslog = (t & 3) ^ ((crow >> 1) & 3);
    size_t xbase = (size_t)x[c0 + crow] * E_;

    float4_t acc[4][4];
#pragma unroll
    for (int mf = 0; mf < 4; mf++)
#pragma unroll
        for (int nf = 0; nf < 4; nf++) acc[mf][nf] = (float4_t){0.f, 0.f, 0.f, 0.f};

    for (int ec = 0; ec < 16; ec++) {
        int e0 = ec * 32;
        {
            const float* src = embf + xbase + e0 + xslog * 8;
            float4 f0 = *(const float4*)(src);
            float4 f1 = *(const float4*)(src + 4);
            short8_t pk;
            pk[0] = (short)f2b(f0.x); pk[1] = (short)f2b(f0.y);
            pk[2] = (short)f2b(f0.z); pk[3] = (short)f2b(f0.w);
            pk[4] = (short)f2b(f1.x); pk[5] = (short)f2b(f1.y);
            pk[6] = (short)f2b(f1.z); pk[7] = (short)f2b(f1.w);
            *(short8_t*)(Xs + t * 8) = pk;
        }
#pragma unroll
        for (int p = 0; p < 4; p++) {
            int idx  = p * 256 + t;
            int arow = idx >> 2;
            int slog = (idx & 3) ^ ((arow >> 1) & 3);
            glds16(T16 + (size_t)arow * E_ + e0 + slog * 8, Ts + (p * 256 + w * 64) * 8);
        }
        __syncthreads();
        int l15 = l & 15, q = l >> 4;
        short8_t af[4], bf[4];
#pragma unroll
        for (int mf = 0; mf < 4; mf++) {
            int row = mf * 16 + l15;
            int kph = q ^ ((row >> 1) & 3);
            af[mf] = *(const short8_t*)(Xs + row * 32 + kph * 8);
        }
#pragma unroll
        for (int nf = 0; nf < 4; nf++) {
            int row = w * 64 + nf * 16 + l15;
            int kph = q ^ ((row >> 1) & 3);
            bf[nf] = *(const short8_t*)(Ts + row * 32 + kph * 8);
        }
#pragma unroll
        for (int mf = 0; mf < 4; mf++)
#pragma unroll
            for (int nf = 0; nf < 4; nf++)
                acc[mf][nf] = __builtin_amdgcn_mfma_f32_16x16x32_bf16(af[mf], bf[nf], acc[mf][nf], 0, 0, 0);
        __syncthreads();
    }

    int l15 = l & 15, q = l >> 4;
    float rta[4];
#pragma unroll
    for (int nf = 0; nf < 4; nf++) rta[nf] = rt[w * 64 + nf * 16 + l15];
#pragma unroll
    for (int mf = 0; mf < 4; mf++) {
#pragma unroll
        for (int r = 0; r < 4; r++) {
            int c = c0 + mf * 16 + q * 4 + r;
            float rxc = rx[c];
            int b = (int)(((unsigned long long)c * 167773ull) >> 25);   // exact c/200 for c<102400
            int s = c - b * 200;
            size_t rowoff = (size_t)(b * 256 + 25 + s) * 256;
#pragma unroll
            for (int nf = 0; nf < 4; nf++) {
                int a = w * 64 + nf * 16 + l15;
                gp2[rowoff + a] = f2b(acc[mf][nf][r] * rta[nf] * rxc);
            }
        }
    }
}

// ================= conv1d(A->A,k=51)+bias+relu+max_a -> m[b,s] =================
__global__ __launch_bounds__(256) void k_conv(const u16* __restrict__ gp2, const u16* __restrict__ ap,
                                              const float* __restrict__ cbf, float* __restrict__ mOut) {
    __shared__ __align__(16) short As[256 * 32];
    __shared__ __align__(16) short Bs[64 * 32];
    __shared__ float wred[4 * 64];
    int t = threadIdx.x, l = t & 63, w = t >> 6;
    int c2_0 = blockIdx.x * 64;
    int brow  = t >> 2;
    int bslog = (t & 3) ^ ((brow >> 1) & 3);

    float4_t acc[4][4];
#pragma unroll
    for (int mf = 0; mf < 4; mf++)
#pragma unroll
        for (int nf = 0; nf < 4; nf++) acc[mf][nf] = (float4_t){0.f, 0.f, 0.f, 0.f};

    for (int kb = 0; kb < 408; kb++) {
        int k = kb >> 3, i0 = (kb & 7) << 5;
#pragma unroll
        for (int p = 0; p < 4; p++) {
            int idx  = p * 256 + t;
            int arow = idx >> 2;
            int slog = (idx & 3) ^ ((arow >> 1) & 3);
            glds16(ap + (size_t)kb * 8192 + arow * 32 + slog * 8, As + (p * 256 + w * 64) * 8);
        }
        glds16(gp2 + (size_t)(c2_0 + brow + k) * 256 + i0 + bslog * 8, Bs + (w * 64) * 8);
        __syncthreads();
        int l15 = l & 15, q = l >> 4;
        short8_t af[4], bfr[4];
#pragma unroll
        for (int mf = 0; mf < 4; mf++) {
            int row = w * 64 + mf * 16 + l15;
            int kph = q ^ ((row >> 1) & 3);
            af[mf] = *(const short8_t*)(As + row * 32 + kph * 8);
        }
#pragma unroll
        for (int nf = 0; nf < 4; nf++) {
            int row = nf * 16 + l15;
            int kph = q ^ ((row >> 1) & 3);
            bfr[nf] = *(const short8_t*)(Bs + row * 32 + kph * 8);
        }
#pragma unroll
        for (int mf = 0; mf < 4; mf++)
#pragma unroll
            for (int nf = 0; nf < 4; nf++)
                acc[mf][nf] = __builtin_amdgcn_mfma_f32_16x16x32_bf16(af[mf], bfr[nf], acc[mf][nf], 0, 0, 0);
        __syncthreads();
    }

    int l15 = l & 15, q = l >> 4;
    float vmax[4] = {0.f, 0.f, 0.f, 0.f};          // relu via 0-init
#pragma unroll
    for (int mf = 0; mf < 4; mf++) {
#pragma unroll
        for (int r = 0; r < 4; r++) {
            float bias = cbf[w * 64 + mf * 16 + q * 4 + r];
#pragma unroll
            for (int nf = 0; nf < 4; nf++)
                vmax[nf] = fmaxf(vmax[nf], acc[mf][nf][r] + bias);
        }
    }
#pragma unroll
    for (int nf = 0; nf < 4; nf++) {
        vmax[nf] = fmaxf(vmax[nf], __shfl_xor(vmax[nf], 16, 64));
        vmax[nf] = fmaxf(vmax[nf], __shfl_xor(vmax[nf], 32, 64));
    }
    if (l < 16) {
#pragma unroll
        for (int nf = 0; nf < 4; nf++) wred[w * 64 + nf * 16 + l] = vmax[nf];
    }
    __syncthreads();
    if (t < 64) {
        float mm = fmaxf(fmaxf(wred[t], wred[64 + t]), fmaxf(wred[128 + t], wred[192 + t]));
        int c2 = c2_0 + t;
        int scol = c2 & 255;
        if (scol < 200) mOut[(c2 >> 8) * 200 + scol] = mm;
    }
}

// ================= FUSED tail: masked softmax -> z_s -> logits -> p_t -> r_s =================
// One block per batch b; 512 threads. ALL outputs f32.
__global__ __launch_bounds__(512) void k_tail(const int* __restrict__ x, const float* __restrict__ embf,
                                              const float* __restrict__ Tf, const float* __restrict__ Wwf,
                                              const float* __restrict__ Wbf, const float* __restrict__ mB,
                                              float* __restrict__ o_pt, float* __restrict__ o_zs,
                                              float* __restrict__ o_rs, float* __restrict__ o_ai,
                                              float* __restrict__ o_ptl) {
    __shared__ float aL[200];
    __shared__ int   tokL[200];
    __shared__ float zL[512];
    __shared__ float pL[256];
    __shared__ float red[512];
    int b = blockIdx.x, t = threadIdx.x;

    // ---- masked softmax over s ----
    float v = 0.f;
    if (t < 200) {
        int tok = x[b * 200 + t];
        tokL[t] = tok;
        v = (tok == PADIDX) ? -1e13f : mB[b * 200 + t];
        red[t] = v;
    }
    __syncthreads();
    float mx = -3.4e38f;
    for (int i = 0; i < 200; i++) mx = fmaxf(mx, red[i]);
    __syncthreads();
    float e = 0.f;
    if (t < 200) { e = expf(v - mx); red[t] = e; }
    __syncthreads();
    float tot = 0.f;
    for (int i = 0; i < 200; i++) tot += red[i];
    float ainv = 1.0f / tot;
    if (t < 200) {
        float a = e * ainv;
        aL[t] = a;
        o_ai[b * 200 + t] = a;
    }
    __syncthreads();

    // ---- z_s[e], e = t in [0,512) ----
    float z = 0.f;
    for (int s = 0; s < 200; s++)
        z += aL[s] * embf[(size_t)tokL[s] * E_ + t];
    zL[t] = z;
    o_zs[b * 512 + t] = z;
    __syncthreads();

    // ---- logits[a], a = t in [0,256) ----
    if (t < 256) {
        float acc = Wbf[t];
        const float* wr = Wwf + (size_t)t * E_;
        for (int e2 = 0; e2 < 512; e2 += 4) {
            float4 w4 = *(const float4*)(wr + e2);
            acc += zL[e2] * w4.x + zL[e2+1] * w4.y + zL[e2+2] * w4.z + zL[e2+3] * w4.w;
        }
        red[t] = acc;
        o_ptl[b * 256 + t] = acc;
    }
    __syncthreads();
    float lmx = -3.4e38f;
    for (int i = 0; i < 256; i++) lmx = fmaxf(lmx, red[i]);
    __syncthreads();
    if (t < 256) red[256 + t] = expf(red[t] - lmx);
    __syncthreads();
    float ptot = 0.f;
    for (int i = 0; i < 256; i++) ptot += red[256 + i];
    float pinv = 1.0f / ptot;
    if (t < 256) {
        float p = red[256 + t] * pinv;
        pL[t] = p;
        o_pt[b * 256 + t] = p;
    }
    __syncthreads();

    // ---- r_s[e] = sum_a p[a] * T[a][e], e = t in [0,512) ----
    float r = 0.f;
    for (int a = 0; a < 256; a++)
        r += pL[a] * Tf[(size_t)a * E_ + t];
    o_rs[b * 512 + t] = r;
}

extern "C" void kernel_launch(void* const* d_in, const int* in_sizes, int n_in,
                              void* d_out, int out_size, void* d_ws, size_t ws_size,
                              hipStream_t stream) {
    if (ws_size < WS_NEEDED) return;
    const int*   x    = (const int*)d_in[0];
    const float* embf = (const float*)d_in[1];
    const float* Tf   = (const float*)d_in[2];
    const float* Wwf  = (const float*)d_in[3];
    const float* Wbf  = (const float*)d_in[4];
    const float* cwf  = (const float*)d_in[5];
    const float* cbf  = (const float*)d_in[6];

    char* ws = (char*)d_ws;
    u16*   gp2 = (u16*)(ws + GP2_OFF);
    u16*   ap  = (u16*)(ws + AP_OFF);
    u16*   T16 = (u16*)(ws + T16_OFF);
    float* rt  = (float*)(ws + RT_OFF);
    float* rx  = (float*)(ws + RX_OFF);
    float* mB  = (float*)(ws + M_OFF);

    float* out   = (float*)d_out;                   // f32 outputs!
    float* o_pt  = out;                 // [B,A]   131072
    float* o_zs  = out + 131072;        // [B,E]   262144
    float* o_rs  = out + 393216;        // [B,E]   262144
    float* o_ai  = out + 655360;        // [B,S]   102400
    float* o_ptl = out + 757760;        // [B,A]   131072  -> total 888832

    hipMemsetAsync(gp2, 0, GP2_BYTES, stream);
    k_cvtT   <<<128,   256, 0, stream>>>(Tf, T16);
    k_tnorm  <<<256,   64,  0, stream>>>(Tf, rt);
    k_xnorm  <<<25600, 256, 0, stream>>>(x, embf, rx);
    k_prepack<<<13056, 256, 0, stream>>>(cwf, ap);
    k_ggemm  <<<1600,  256, 0, stream>>>(x, embf, T16, rt, rx, gp2);
    k_conv   <<<2048,  256, 0, stream>>>(gp2, ap, cbf, mB);
    k_tail   <<<512,   512, 0, stream>>>(x, embf, Tf, Wwf, Wbf, mB, o_pt, o_zs, o_rs, o_ai, o_ptl);
}

// Round 6
// 728.262 us; speedup vs baseline: 1.5897x; 1.5897x over previous
//
#include <hip/hip_runtime.h>

#define B_  512
#define S_  200
#define E_  512
#define A_  256
#define V_  50000
#define K_  51
#define PADIDX 1

typedef short short8_t __attribute__((ext_vector_type(8)));
typedef float float4_t __attribute__((ext_vector_type(4)));
typedef int   int8v    __attribute__((ext_vector_type(8)));
typedef unsigned short u16;
typedef unsigned int   u32;
typedef unsigned char  u8;

// ---------- f32 -> bf16 RNE (internal staging only) ----------
__device__ __forceinline__ u16 f2b(float f) {
    u32 x = __float_as_uint(f);
    return (u16)((x + 0x7fffu + ((x >> 16) & 1u)) >> 16);
}
// ---------- f32 -> fp8 e4m3 (OCP), via HW cvt ----------
__device__ __forceinline__ u8 f2fp8(float f) {
    int p = __builtin_amdgcn_cvt_pk_fp8_f32(f, 0.f, 0, false);
    return (u8)(p & 0xff);
}

// ---------- async global->LDS, 16B per lane ----------
__device__ __forceinline__ void glds16(const u16* g, short* l) {
    __builtin_amdgcn_global_load_lds(
        (const __attribute__((address_space(1))) unsigned int*)g,
        (__attribute__((address_space(3))) unsigned int*)l, 16, 0, 0);
}
__device__ __forceinline__ void glds16b(const u8* g, const u8* l) {
    __builtin_amdgcn_global_load_lds(
        (const __attribute__((address_space(1))) unsigned int*)g,
        (__attribute__((address_space(3))) unsigned int*)l, 16, 0, 0);
}

// ---------- workspace offsets (bytes); total guard 76,628,992 (proven) ----------
#define GP8_OFF   0ull
#define GP8_BYTES 33587200ull          // 131072 rows * 256 fp8 + 32KB slack
#define AP2_OFF   33587200ull          // packed+swizzled conv weights: 102*32768 fp8
#define RT_OFF    36929536ull          // 1/||T_a||   (256 f32)
#define RX_OFF    36930560ull          // 1/||xx_c||  (102400 f32)
#define M_OFF     37340160ull          // m[b,s]      (102400 f32)
#define T16_OFF   37749760ull          // T in bf16 (512KB)
#define WS_NEEDED 76628992ull

// ================= T (f32) -> bf16 =================
__global__ __launch_bounds__(256) void k_cvtT(const float* __restrict__ Tf, u16* __restrict__ T16) {
    int o = (blockIdx.x * 256 + threadIdx.x) * 4;
    float4 d = *(const float4*)(Tf + o);
    ushort4 r;
    r.x = f2b(d.x); r.y = f2b(d.y); r.z = f2b(d.z); r.w = f2b(d.w);
    *(ushort4*)(T16 + o) = r;
}

// ================= 1/||T_a|| =================
__global__ __launch_bounds__(64) void k_tnorm(const float* __restrict__ Tf, float* __restrict__ rt) {
    int a = blockIdx.x, l = threadIdx.x;
    float4 d0 = *(const float4*)(Tf + (size_t)a * E_ + l * 8);
    float4 d1 = *(const float4*)(Tf + (size_t)a * E_ + l * 8 + 4);
    float s = d0.x*d0.x + d0.y*d0.y + d0.z*d0.z + d0.w*d0.w
            + d1.x*d1.x + d1.y*d1.y + d1.z*d1.z + d1.w*d1.w;
#pragma unroll
    for (int off = 32; off >= 1; off >>= 1) s += __shfl_xor(s, off, 64);
    if (l == 0) rt[a] = (s > 0.f) ? 1.0f / sqrtf(s) : 0.0f;
}

// ================= 1/||emb[x_c]|| =================
__global__ __launch_bounds__(256) void k_xnorm(const int* __restrict__ x, const float* __restrict__ embf,
                                               float* __restrict__ rx) {
    int c = blockIdx.x * 4 + (threadIdx.x >> 6);
    int l = threadIdx.x & 63;
    size_t base = (size_t)x[c] * E_ + l * 8;
    float4 d0 = *(const float4*)(embf + base);
    float4 d1 = *(const float4*)(embf + base + 4);
    float s = d0.x*d0.x + d0.y*d0.y + d0.z*d0.z + d0.w*d0.w
            + d1.x*d1.x + d1.y*d1.y + d1.z*d1.z + d1.w*d1.w;
#pragma unroll
    for (int off = 32; off >= 1; off >>= 1) s += __shfl_xor(s, off, 64);
    if (l == 0) rx[c] = (s > 0.f) ? 1.0f / sqrtf(s) : 0.0f;
}

// ========= pack conv_w (f32) -> ap2[kb][a][granule-swizzled 128B] fp8, scaled x512 =========
// Layout: chunk kb (128 k), row a: 8 granules of 16B; phys granule gslot holds logical
// granule gslot^(a&7). Logical k within chunk = lg*16+j; global kk = kb*128+k; tap=kk>>8, i=kk&255.
__global__ __launch_bounds__(256) void k_prepack(const float* __restrict__ cwf, u8* __restrict__ ap2) {
    int o = blockIdx.x * 256 + threadIdx.x;          // 102*32768 total
    int kb = o >> 15;
    int rem = o & 32767;
    int row = rem >> 7;
    int gslot = (rem >> 4) & 7;
    int j = o & 15;
    int lg = gslot ^ (row & 7);
    int kk = (kb << 7) + (lg << 4) + j;
    int tap = kk >> 8, i = kk & 255;
    float v = cwf[(size_t)row * (A_ * K_) + (size_t)i * K_ + tap] * 512.0f;
    ap2[o] = f2fp8(v);
}

// ================= g = cosine(T, emb[x]) -> gp8[(b*256+25+s)*256 + a] fp8 (x32) =================
__global__ __launch_bounds__(256) void k_ggemm(const int* __restrict__ x, const float* __restrict__ embf,
                                               const u16* __restrict__ T16, const float* __restrict__ rt,
                                               const float* __restrict__ rx, u8* __restrict__ gp8) {
    __shared__ __align__(16) short Xs[64 * 32];
    __shared__ __align__(16) short Ts[256 * 32];
    int t = threadIdx.x, l = t & 63, w = t >> 6;
    int c0 = blockIdx.x * 64;
    int crow  = t >> 2;
    int xslog = (t & 3) ^ ((crow >> 1) & 3);
    size_t xbase = (size_t)x[c0 + crow] * E_;

    float4_t acc[4][4];
#pragma unroll
    for (int mf = 0; mf < 4; mf++)
#pragma unroll
        for (int nf = 0; nf < 4; nf++) acc[mf][nf] = (float4_t){0.f, 0.f, 0.f, 0.f};

    for (int ec = 0; ec < 16; ec++) {
        int e0 = ec * 32;
        {
            const float* src = embf + xbase + e0 + xslog * 8;
            float4 f0 = *(const float4*)(src);
            float4 f1 = *(const float4*)(src + 4);
            short8_t pk;
            pk[0] = (short)f2b(f0.x); pk[1] = (short)f2b(f0.y);
            pk[2] = (short)f2b(f0.z); pk[3] = (short)f2b(f0.w);
            pk[4] = (short)f2b(f1.x); pk[5] = (short)f2b(f1.y);
            pk[6] = (short)f2b(f1.z); pk[7] = (short)f2b(f1.w);
            *(short8_t*)(Xs + t * 8) = pk;
        }
#pragma unroll
        for (int p = 0; p < 4; p++) {
            int idx  = p * 256 + t;
            int arow = idx >> 2;
            int slog = (idx & 3) ^ ((arow >> 1) & 3);
            glds16(T16 + (size_t)arow * E_ + e0 + slog * 8, Ts + (p * 256 + w * 64) * 8);
        }
        __syncthreads();
        int l15 = l & 15, q = l >> 4;
        short8_t af[4], bf[4];
#pragma unroll
        for (int mf = 0; mf < 4; mf++) {
            int row = mf * 16 + l15;
            int kph = q ^ ((row >> 1) & 3);
            af[mf] = *(const short8_t*)(Xs + row * 32 + kph * 8);
        }
#pragma unroll
        for (int nf = 0; nf < 4; nf++) {
            int row = w * 64 + nf * 16 + l15;
            int kph = q ^ ((row >> 1) & 3);
            bf[nf] = *(const short8_t*)(Ts + row * 32 + kph * 8);
        }
#pragma unroll
        for (int mf = 0; mf < 4; mf++)
#pragma unroll
            for (int nf = 0; nf < 4; nf++)
                acc[mf][nf] = __builtin_amdgcn_mfma_f32_16x16x32_bf16(af[mf], bf[nf], acc[mf][nf], 0, 0, 0);
        __syncthreads();
    }

    int l15 = l & 15, q = l >> 4;
    float rta[4];
#pragma unroll
    for (int nf = 0; nf < 4; nf++) rta[nf] = rt[w * 64 + nf * 16 + l15];
#pragma unroll
    for (int mf = 0; mf < 4; mf++) {
#pragma unroll
        for (int r = 0; r < 4; r++) {
            int c = c0 + mf * 16 + q * 4 + r;
            float rxc = rx[c] * 32.0f;                                  // fp8 pre-scale
            int b = (int)(((unsigned long long)c * 167773ull) >> 25);   // exact c/200
            int s = c - b * 200;
            size_t rowoff = (size_t)(b * 256 + 25 + s) * 256;
#pragma unroll
            for (int nf = 0; nf < 4; nf++) {
                int a = w * 64 + nf * 16 + l15;
                gp8[rowoff + a] = f2fp8(acc[mf][nf][r] * rta[nf] * rxc);
            }
        }
    }
}

// ================= conv1d(A->A,k=51)+bias+relu+max_a -> m[col], packed N =================
// MX-fp8 16x16x128, unit scales. M=256(a) x N=64(packed cols) x BK=128, 102 chunks.
__global__ __launch_bounds__(256) void k_conv(const u8* __restrict__ gp8, const u8* __restrict__ ap2,
                                              const float* __restrict__ cbf, float* __restrict__ mOut) {
    __shared__ __align__(16) u8 As[256 * 128];   // 32 KB
    __shared__ __align__(16) u8 Bs[64 * 128];    // 8 KB
    __shared__ float wred[256];
    int t = threadIdx.x, l = t & 63, w = t >> 6;
    int c0 = blockIdx.x * 64;

    // B-staging per-thread bases (2 rounds): row_p = p*32 + (t>>3), gslot = t&7
    size_t srcb[2];
#pragma unroll
    for (int p = 0; p < 2; p++) {
        int row = p * 32 + (t >> 3);
        int c = c0 + row;
        int b = (int)(((unsigned long long)c * 167773ull) >> 25);
        int s = c - b * 200;
        int gsw = (t & 7) ^ (row & 7);
        srcb[p] = (size_t)(b * 256 + s) * 256 + gsw * 16;
    }

    float4_t acc[4][4];
#pragma unroll
    for (int mf = 0; mf < 4; mf++)
#pragma unroll
        for (int nf = 0; nf < 4; nf++) acc[mf][nf] = (float4_t){0.f, 0.f, 0.f, 0.f};

    for (int kb = 0; kb < 102; kb++) {
        // A: 8 linear rounds (ap2 pre-swizzled)
#pragma unroll
        for (int p = 0; p < 8; p++)
            glds16b(ap2 + ((size_t)kb << 15) + (p << 12) + (t << 4), As + (p << 12) + (w << 10));
        // B: 2 rounds; chunk byte offset within row = kb*128 (tap*256 + ihalf*128 == kb<<7)
        glds16b(gp8 + srcb[0] + ((size_t)kb << 7), Bs + (w << 10));
        glds16b(gp8 + srcb[1] + ((size_t)kb << 7), Bs + 4096 + (w << 10));
        __syncthreads();

        int l15 = l & 15, kq = l >> 4;
        int8v af[4], bfr[4];
#pragma unroll
        for (int mf = 0; mf < 4; mf++) {
            int row = (w << 6) + (mf << 4) + l15;
            int sw = row & 7;
            const u8* base = As + (row << 7);
            int4 lo = *(const int4*)(base + ((((kq << 1)    ) ^ sw) << 4));
            int4 hi = *(const int4*)(base + ((((kq << 1) | 1) ^ sw) << 4));
            int8v v; v[0]=lo.x; v[1]=lo.y; v[2]=lo.z; v[3]=lo.w; v[4]=hi.x; v[5]=hi.y; v[6]=hi.z; v[7]=hi.w;
            af[mf] = v;
        }
#pragma unroll
        for (int nf = 0; nf < 4; nf++) {
            int row = (nf << 4) + l15;
            int sw = row & 7;
            const u8* base = Bs + (row << 7);
            int4 lo = *(const int4*)(base + ((((kq << 1)    ) ^ sw) << 4));
            int4 hi = *(const int4*)(base + ((((kq << 1) | 1) ^ sw) << 4));
            int8v v; v[0]=lo.x; v[1]=lo.y; v[2]=lo.z; v[3]=lo.w; v[4]=hi.x; v[5]=hi.y; v[6]=hi.z; v[7]=hi.w;
            bfr[nf] = v;
        }
#pragma unroll
        for (int mf = 0; mf < 4; mf++)
#pragma unroll
            for (int nf = 0; nf < 4; nf++)
                acc[mf][nf] = __builtin_amdgcn_mfma_scale_f32_16x16x128_f8f6f4(
                    af[mf], bfr[nf], acc[mf][nf], 0, 0, 0, 0x7F7F7F7F, 0, 0x7F7F7F7F);
        __syncthreads();
    }

    // epilogue: undo 2^14 quant scale, +bias, relu (0-init), max over a
    const float SC = 6.103515625e-05f;   // 2^-14
    int l15 = l & 15, q = l >> 4;
    float vmax[4] = {0.f, 0.f, 0.f, 0.f};
#pragma unroll
    for (int mf = 0; mf < 4; mf++) {
#pragma unroll
        for (int r = 0; r < 4; r++) {
            float bias = cbf[w * 64 + mf * 16 + q * 4 + r];
#pragma unroll
            for (int nf = 0; nf < 4; nf++)
                vmax[nf] = fmaxf(vmax[nf], acc[mf][nf][r] * SC + bias);
        }
    }
#pragma unroll
    for (int nf = 0; nf < 4; nf++) {
        vmax[nf] = fmaxf(vmax[nf], __shfl_xor(vmax[nf], 16, 64));
        vmax[nf] = fmaxf(vmax[nf], __shfl_xor(vmax[nf], 32, 64));
    }
    if (l < 16) {
#pragma unroll
        for (int nf = 0; nf < 4; nf++) wred[w * 64 + nf * 16 + l] = vmax[nf];
    }
    __syncthreads();
    if (t < 64) {
        float mm = fmaxf(fmaxf(wred[t], wred[64 + t]), fmaxf(wred[128 + t], wred[192 + t]));
        mOut[c0 + t] = mm;     // packed: col == b*200+s
    }
}

// ================= FUSED tail: masked softmax -> z_s -> logits -> p_t -> r_s =================
__global__ __launch_bounds__(512) void k_tail(const int* __restrict__ x, const float* __restrict__ embf,
                                              const float* __restrict__ Tf, const float* __restrict__ Wwf,
                                              const float* __restrict__ Wbf, const float* __restrict__ mB,
                                              float* __restrict__ o_pt, float* __restrict__ o_zs,
                                              float* __restrict__ o_rs, float* __restrict__ o_ai,
                                              float* __restrict__ o_ptl) {
    __shared__ float aL[200];
    __shared__ int   tokL[200];
    __shared__ float zL[512];
    __shared__ float pL[256];
    __shared__ float red[512];
    int b = blockIdx.x, t = threadIdx.x;

    float v = 0.f;
    if (t < 200) {
        int tok = x[b * 200 + t];
        tokL[t] = tok;
        v = (tok == PADIDX) ? -1e13f : mB[b * 200 + t];
        red[t] = v;
    }
    __syncthreads();
    float mx = -3.4e38f;
    for (int i = 0; i < 200; i++) mx = fmaxf(mx, red[i]);
    __syncthreads();
    float e = 0.f;
    if (t < 200) { e = expf(v - mx); red[t] = e; }
    __syncthreads();
    float tot = 0.f;
    for (int i = 0; i < 200; i++) tot += red[i];
    float ainv = 1.0f / tot;
    if (t < 200) {
        float a = e * ainv;
        aL[t] = a;
        o_ai[b * 200 + t] = a;
    }
    __syncthreads();

    float z = 0.f;
    for (int s = 0; s < 200; s++)
        z += aL[s] * embf[(size_t)tokL[s] * E_ + t];
    zL[t] = z;
    o_zs[b * 512 + t] = z;
    __syncthreads();

    if (t < 256) {
        float acc = Wbf[t];
        const float* wr = Wwf + (size_t)t * E_;
        for (int e2 = 0; e2 < 512; e2 += 4) {
            float4 w4 = *(const float4*)(wr + e2);
            acc += zL[e2] * w4.x + zL[e2+1] * w4.y + zL[e2+2] * w4.z + zL[e2+3] * w4.w;
        }
        red[t] = acc;
        o_ptl[b * 256 + t] = acc;
    }
    __syncthreads();
    float lmx = -3.4e38f;
    for (int i = 0; i < 256; i++) lmx = fmaxf(lmx, red[i]);
    __syncthreads();
    if (t < 256) red[256 + t] = expf(red[t] - lmx);
    __syncthreads();
    float ptot = 0.f;
    for (int i = 0; i < 256; i++) ptot += red[256 + i];
    float pinv = 1.0f / ptot;
    if (t < 256) {
        float p = red[256 + t] * pinv;
        pL[t] = p;
        o_pt[b * 256 + t] = p;
    }
    __syncthreads();

    float r = 0.f;
    for (int a = 0; a < 256; a++)
        r += pL[a] * Tf[(size_t)a * E_ + t];
    o_rs[b * 512 + t] = r;
}

extern "C" void kernel_launch(void* const* d_in, const int* in_sizes, int n_in,
                              void* d_out, int out_size, void* d_ws, size_t ws_size,
                              hipStream_t stream) {
    if (ws_size < WS_NEEDED) return;
    const int*   x    = (const int*)d_in[0];
    const float* embf = (const float*)d_in[1];
    const float* Tf   = (const float*)d_in[2];
    const float* Wwf  = (const float*)d_in[3];
    const float* Wbf  = (const float*)d_in[4];
    const float* cwf  = (const float*)d_in[5];
    const float* cbf  = (const float*)d_in[6];

    char* ws = (char*)d_ws;
    u8*    gp8 = (u8*)(ws + GP8_OFF);
    u8*    ap2 = (u8*)(ws + AP2_OFF);
    u16*   T16 = (u16*)(ws + T16_OFF);
    float* rt  = (float*)(ws + RT_OFF);
    float* rx  = (float*)(ws + RX_OFF);
    float* mB  = (float*)(ws + M_OFF);

    float* out   = (float*)d_out;
    float* o_pt  = out;                 // [B,A]
    float* o_zs  = out + 131072;        // [B,E]
    float* o_rs  = out + 393216;        // [B,E]
    float* o_ai  = out + 655360;        // [B,S]
    float* o_ptl = out + 757760;        // [B,A]

    hipMemsetAsync(gp8, 0, GP8_BYTES, stream);
    k_cvtT   <<<128,   256, 0, stream>>>(Tf, T16);
    k_tnorm  <<<256,   64,  0, stream>>>(Tf, rt);
    k_xnorm  <<<25600, 256, 0, stream>>>(x, embf, rx);
    k_prepack<<<13056, 256, 0, stream>>>(cwf, ap2);
    k_ggemm  <<<1600,  256, 0, stream>>>(x, embf, T16, rt, rx, gp8);
    k_conv   <<<1600,  256, 0, stream>>>(gp8, ap2, cbf, mB);
    k_tail   <<<512,   512, 0, stream>>>(x, embf, Tf, Wwf, Wbf, mB, o_pt, o_zs, o_rs, o_ai, o_ptl);
}